// Round 26
// baseline (98.606 us; speedup 1.0000x reference)
//
#include <hip/hip_runtime.h>
#include <math.h>

// Problem constants
#define BB    16                 // batch
#define HH    112                // input H == W
#define IMSZ  (HH*HH)            // 12544 floats per image plane
#define OO    256                // output channels
#define OTILE 16                 // o's per block
#define OHW   108                // output H == W
#define PLANE (OHW*OHW)          // 11664 pixels per (b,o) plane
#define NFRAG (PLANE/16)         // 729 16-px fragments per plane
#define WRECB 144                // weight record bytes: hi[64] | lo[64] | pad[16]
#define WRECW 36                 // record size in u32 words
#define NXCD  8

typedef __attribute__((ext_vector_type(8))) short short8;   // 8 bf16 = 4 VGPR
typedef __attribute__((ext_vector_type(4))) float f32x4;

// round-to-nearest-even float -> bf16 (bit trick; inputs finite)
__device__ __forceinline__ unsigned short f2bf(float x) {
    unsigned u = __builtin_bit_cast(unsigned, x);
    return (unsigned short)((u + 0x7fffu + ((u >> 16) & 1u)) >> 16);
}
__device__ __forceinline__ float bf2f(unsigned short h) {
    unsigned u = ((unsigned)h) << 16;
    return __builtin_bit_cast(float, u);
}

// GEMM formulation: xw[p,o] = sum_k win[p][k] * w[o][k], K=25 padded to 32.
// bf16 hi/lo split, 3 MFMAs (hh, hl, lh) per image; d2 = x2 + w2 - 2*xw;
// (sqrt(a)+sqrt(b))^2 = a + b + 2*sqrt(a*b) -> 1 sqrt + 1 exp per output.
// R26: FILL-LIKE REGION OWNERSHIP. block = (b, 16-o tile) -> 256 blocks,
// each writing ONE contiguous 746KB output region (16 planes x 46.6KB) --
// the same per-workgroup write shape as the 6.6 TB/s fill kernel. 16 long
// streams/block vs R25's 256 short ones; 100% CU coverage, solo residency.
// Cost: A rebuilt per block-visit (16x chip-wide, ~+13us VALU) -- still
// under the ~29us write floor. B-weights live in REGISTERS (16 VGPR/wave);
// LDS shrinks to 4.7KB (staging only).
__global__ __launch_bounds__(1024)
void dist_rbf_mfma(const float* __restrict__ gx, const float* __restrict__ rx,
                   const float* __restrict__ gw, const float* __restrict__ rw,
                   const float* __restrict__ stdp, float* __restrict__ out)
{
    __shared__ __align__(16) unsigned wrec[2 * OTILE * WRECW];  // 4.6 KB
    __shared__ float w2s[2 * OTILE];

    const int tid = threadIdx.x;

    // ---- XCD swizzle: 256 % 8 == 0 -> simple bijective remap ----
    const int lbk   = (blockIdx.x & (NXCD - 1)) * (256 / NXCD) + (blockIdx.x >> 3);
    const int b     = lbk >> 4;             // batch
    const int obase = (lbk & 15) * OTILE;   // o-tile base

    // ---- stage 32 weight records (2 img x 16 o) into LDS ----
    if (tid < 2 * OTILE) {
        const int img = tid >> 4;
        const int ol  = tid & 15;
        const float* wsrc = (img ? rw : gw) + (size_t)(obase + ol) * 25;
        unsigned* rec = wrec + (img * OTILE + ol) * WRECW;
        float v[32]; unsigned short h[32];
        float s = 0.f;
        #pragma unroll
        for (int i = 0; i < 32; i++) {
            float x = (i < 25) ? wsrc[i] : 0.f;
            v[i] = x; s = fmaf(x, x, s); h[i] = f2bf(x);
        }
        w2s[img * OTILE + ol] = s;
        #pragma unroll
        for (int wd = 0; wd < 16; wd++) {
            rec[wd] = (unsigned)h[2*wd] | ((unsigned)h[2*wd+1] << 16);
            unsigned short l0 = f2bf(v[2*wd]   - bf2f(h[2*wd]));
            unsigned short l1 = f2bf(v[2*wd+1] - bf2f(h[2*wd+1]));
            rec[16 + wd] = (unsigned)l0 | ((unsigned)l1 << 16);
        }
    }
    __syncthreads();

    const int lid  = tid & 63;
    const int wid  = tid >> 6;     // 16 waves
    const int mcol = lid & 15;     // A: pixel row within frag; B/C: o col
    const int kgrp = lid >> 4;     // k-group: k in [kgrp*8, kgrp*8+8)
    const int k0   = kgrp * 8;

    const float sd   = stdp[0];
    const float kneg = -1.f / (2.f * sd * sd);

    // ---- load this lane's B fragments into REGISTERS (once) ----
    const char* wrecB = (const char*)wrec;
    const char* recg = wrecB + (size_t)mcol * WRECB + kgrp * 16;
    const char* recr = recg + (size_t)OTILE * WRECB;
    const short8 bhg = *(const short8*)recg;
    const short8 blg = *(const short8*)(recg + 64);
    const short8 bhr = *(const short8*)recr;
    const short8 blr = *(const short8*)(recr + 64);
    const float  w2g = w2s[mcol];
    const float  w2r = w2s[OTILE + mcol];

    const float* gsrc = gx + (size_t)b * IMSZ;
    const float* rsrc = rx + (size_t)b * IMSZ;
    // block's contiguous output region; lane's plane = obase + mcol
    float* outp = out + ((size_t)(b * OO + obase + mcol)) * PLANE;

    // ------------- main loop: wave w handles frags w, w+16, ... -------------
    for (int f = wid; f < NFRAG; f += 16) {
        // ---- build A fragment + x2 (pixel row = f*16 + mcol) ----
        const int p  = f * 16 + mcol;
        const int oh = p / OHW;
        const int ow = p - oh * OHW;
        const size_t ibase = (size_t)oh * HH + ow;

        short8 ah[2], al[2];
        float  x2v[2][4];
        #pragma unroll
        for (int img = 0; img < 2; img++) {
            const float* src = (img == 0 ? gsrc : rsrc) + ibase;
            float xs[8];
            float part = 0.f;
            #pragma unroll
            for (int j = 0; j < 8; j++) {
                int k = k0 + j;
                int r2 = k / 5, c2 = k - r2 * 5;
                float x = (k < 25) ? src[r2 * HH + c2] : 0.f;
                xs[j] = x; part = fmaf(x, x, part);
            }
            // reduce partial x2 across the 4 k-groups of this pixel
            part += __shfl_xor(part, 16);
            part += __shfl_xor(part, 32);
            // fetch x2 for the epilogue's C rows (pixels f*16 + kgrp*4 + rr)
            #pragma unroll
            for (int rr = 0; rr < 4; rr++)
                x2v[img][rr] = __shfl(part, kgrp * 4 + rr);
            // bf16 hi/lo split
            short8 hi, lo;
            #pragma unroll
            for (int j = 0; j < 8; j++) {
                unsigned short hh = f2bf(xs[j]);
                hi[j] = (short)hh;
                lo[j] = (short)f2bf(xs[j] - bf2f(hh));
            }
            ah[img] = hi; al[img] = lo;
        }

        // ---- 6 MFMAs: all 16 o's of the tile at once ----
        f32x4 cg = {0.f, 0.f, 0.f, 0.f};
        f32x4 cr = {0.f, 0.f, 0.f, 0.f};
        cg = __builtin_amdgcn_mfma_f32_16x16x32_bf16(ah[0], bhg, cg, 0, 0, 0);
        cg = __builtin_amdgcn_mfma_f32_16x16x32_bf16(ah[0], blg, cg, 0, 0, 0);
        cg = __builtin_amdgcn_mfma_f32_16x16x32_bf16(al[0], bhg, cg, 0, 0, 0);
        cr = __builtin_amdgcn_mfma_f32_16x16x32_bf16(ah[1], bhr, cr, 0, 0, 0);
        cr = __builtin_amdgcn_mfma_f32_16x16x32_bf16(ah[1], blr, cr, 0, 0, 0);
        cr = __builtin_amdgcn_mfma_f32_16x16x32_bf16(al[1], bhr, cr, 0, 0, 0);

        // ---- epilogue: 4 outputs = pixels f*16 + kgrp*4 + rr, plane obase+mcol ----
        f32x4 res;
        #pragma unroll
        for (int rr = 0; rr < 4; rr++) {
            float d2g = fmaf(-2.f, cg[rr], x2v[0][rr] + w2g);
            float d2r = fmaf(-2.f, cr[rr], x2v[1][rr] + w2r);
            d2g = fmaxf(d2g, 1e-12f);
            d2r = fmaxf(d2r, 1e-12f);
            // (sqrt(d2g)+sqrt(d2r))^2 = d2g + d2r + 2*sqrt(d2g*d2r)
            float d2 = fmaf(2.f, __builtin_amdgcn_sqrtf(d2g * d2r), d2g + d2r);
            res[rr] = __expf(kneg * d2);
        }
        // frag lies wholly inside the plane (f*16+16 <= PLANE); one dwordx4
        *(f32x4*)(outp + f * 16 + kgrp * 4) = res;
    }
}

extern "C" void kernel_launch(void* const* d_in, const int* in_sizes, int n_in,
                              void* d_out, int out_size, void* d_ws, size_t ws_size,
                              hipStream_t stream) {
    const float* gx   = (const float*)d_in[0];
    const float* rx   = (const float*)d_in[1];
    const float* gw   = (const float*)d_in[2];
    const float* rw   = (const float*)d_in[3];
    const float* stdp = (const float*)d_in[4];
    float* out = (float*)d_out;

    dim3 grid(BB * (OO / OTILE), 1, 1);   // 256 blocks: one (b, o-tile) each
    dim3 block(1024, 1, 1);
    dist_rbf_mfma<<<grid, block, 0, stream>>>(gx, rx, gw, rw, stdp, out);
}